// Round 5
// baseline (694.982 us; speedup 1.0000x reference)
//
#include <hip/hip_runtime.h>
#include <math.h>

// Problem constants
#define D_ELEMS 25088   // C*H*W = 512*7*7
#define D4      6272    // D_ELEMS / 4
#define N_MEM   2000
#define B_KEYS  32
#define PI_2F   1.570795f   // 3.14159 / 2, matches reference
#define EPSF    1e-8f
#define NSLICE  16          // k-slices for k_dots_mfma (2000 waves = 2/SIMD)
#define KSLICE  1568        // 25088 / 16
#define KSTEPS  49          // KSLICE / 32

using short8 = __attribute__((ext_vector_type(8))) short;   // 8 bf16 A/B frag
using short4v = __attribute__((ext_vector_type(4))) short;
using f32x4  = __attribute__((ext_vector_type(4))) float;   // C/D frag

// ws layout (floats):
//   keyb (bf16 keys, as shorts)   : [0, 401408)
//   dots_part [16][2000][32]      : [401408, 1425408)
//   mn2_part  [16][2000]          : [1425408, 1457408)
//   w         [2000][32]          : [1457408, 1521408)
//   partial [ns][32][25088]       : [1521408, +ns*802816)

__device__ inline short f2bf(float x) {   // fp32 -> bf16 RNE (inputs finite)
    union { float f; unsigned u; } v; v.f = x;
    unsigned r = v.u + 0x7fffu + ((v.u >> 16) & 1u);
    return (short)(r >> 16);
}

// Convert keys fp32 -> bf16 once. 802816 elems, 4 per thread.
__global__ __launch_bounds__(256) void k_prep(const float* __restrict__ key,
                                              short* __restrict__ keyb) {
    const int i = blockIdx.x * 256 + threadIdx.x;   // float4 index, grid 784*256
    const float4 f = ((const float4*)key)[i];
    short4v s; s[0] = f2bf(f.x); s[1] = f2bf(f.y); s[2] = f2bf(f.z); s[3] = f2bf(f.w);
    ((short4v*)keyb)[i] = s;
}

// dots_part[s][n][b] = sum_{k in slice s} key[b][k]*mem[n][k]  (bf16 MFMA)
// mn2_part[s][n]     = sum_{k in slice s} mem[n][k]^2          (fp32)
// grid: 125 n-tiles x 16 slices = 2000 blocks of 1 wave. Depth-2 prefetch:
// 4 KB of mem-stream in flight per wave, 2 waves/SIMD.
__global__ __launch_bounds__(64) void k_dots_mfma(const short* __restrict__ keyb,
                                                  const float* __restrict__ mem,
                                                  float* __restrict__ dots_part,
                                                  float* __restrict__ mn2_part) {
    const int nt   = blockIdx.x / NSLICE;     // 0..124
    const int s    = blockIdx.x % NSLICE;     // 0..15
    const int n0   = nt * 16;
    const int lane = threadIdx.x;             // 0..63
    const int quad = lane >> 4;
    const int l16  = lane & 15;
    const int k0   = s * KSLICE + quad * 8;   // this lane's k base (floats)

    const short* a0p = keyb + (size_t)l16 * D_ELEMS + k0;          // keys 0..15
    const short* a1p = keyb + (size_t)(16 + l16) * D_ELEMS + k0;   // keys 16..31
    const float4* bp = (const float4*)(mem + (size_t)(n0 + l16) * D_ELEMS + k0);

    f32x4 acc0 = {0.f, 0.f, 0.f, 0.f};
    f32x4 acc1 = {0.f, 0.f, 0.f, 0.f};
    float msq = 0.f;

    short8 a0b[2], a1b[2];
    float4 f0b[2], f1b[2];
#pragma unroll
    for (int p = 0; p < 2; ++p) {             // KSTEPS >= 2 always
        a0b[p] = *(const short8*)(a0p + p * 32);
        a1b[p] = *(const short8*)(a1p + p * 32);
        f0b[p] = bp[p * 8];
        f1b[p] = bp[p * 8 + 1];
    }

    for (int t = 0; t < KSTEPS; ++t) {
        const int cur = t & 1;
        const short8 a0c = a0b[cur], a1c = a1b[cur];
        const float4 f0c = f0b[cur], f1c = f1b[cur];
        if (t + 2 < KSTEPS) {                 // wave-uniform branch
            const int tn = t + 2;
            a0b[cur] = *(const short8*)(a0p + tn * 32);
            a1b[cur] = *(const short8*)(a1p + tn * 32);
            f0b[cur] = bp[tn * 8];
            f1b[cur] = bp[tn * 8 + 1];
        }
        msq += f0c.x * f0c.x + f0c.y * f0c.y + f0c.z * f0c.z + f0c.w * f0c.w
             + f1c.x * f1c.x + f1c.y * f1c.y + f1c.z * f1c.z + f1c.w * f1c.w;
        short8 b;
        b[0] = f2bf(f0c.x); b[1] = f2bf(f0c.y); b[2] = f2bf(f0c.z); b[3] = f2bf(f0c.w);
        b[4] = f2bf(f1c.x); b[5] = f2bf(f1c.y); b[6] = f2bf(f1c.z); b[7] = f2bf(f1c.w);
        acc0 = __builtin_amdgcn_mfma_f32_16x16x32_bf16(a0c, b, acc0, 0, 0, 0);
        acc1 = __builtin_amdgcn_mfma_f32_16x16x32_bf16(a1c, b, acc1, 0, 0, 0);
    }

    // D[row=quad*4+r][col=l16]; row = key index (per m-half), col = n index
    float* dp = dots_part + (size_t)(s * N_MEM + n0 + l16) * B_KEYS;
#pragma unroll
    for (int r = 0; r < 4; ++r) {
        dp[quad * 4 + r]      = acc0[r];
        dp[16 + quad * 4 + r] = acc1[r];
    }

    // reduce msq across the 4 quads of each n-row (lanes l16, l16+16, ...)
    msq += __shfl_xor(msq, 16, 64);
    msq += __shfl_xor(msq, 32, 64);
    if (lane < 16) mn2_part[s * N_MEM + n0 + lane] = msq;
}

// per-b: k_norm (fp32 keys), sum 16 slice partials -> cos -> tan -> softmax.
__global__ __launch_bounds__(512) void k_softmax(const float* __restrict__ key,
                                                 const float* __restrict__ dots_part,
                                                 const float* __restrict__ mn2_part,
                                                 float* __restrict__ w) {
    const int b   = blockIdx.x;
    const int tid = threadIdx.x;
    __shared__ float sred[512];
    __shared__ float xbuf[N_MEM];

    const float4* K4 = (const float4*)(key + (size_t)b * D_ELEMS);
    float ks = 0.f;
    for (int i = tid; i < D4; i += 512) {
        float4 kf = K4[i];
        ks += kf.x * kf.x + kf.y * kf.y + kf.z * kf.z + kf.w * kf.w;
    }
    sred[tid] = ks;
    __syncthreads();
    for (int o = 256; o; o >>= 1) {
        if (tid < o) sred[tid] += sred[tid + o];
        __syncthreads();
    }
    const float knorm = fmaxf(sqrtf(sred[0]), EPSF);
    __syncthreads();

    float mx = -1e30f;
    for (int n = tid; n < N_MEM; n += 512) {
        float ds = 0.f, ms = 0.f;
#pragma unroll
        for (int s = 0; s < NSLICE; ++s) ds += dots_part[(size_t)(s * N_MEM + n) * B_KEYS + b];
#pragma unroll
        for (int s = 0; s < NSLICE; ++s) ms += mn2_part[s * N_MEM + n];
        float mn = fmaxf(sqrtf(ms), EPSF);
        float x  = __tanf((ds / (knorm * mn)) * PI_2F);
        xbuf[n] = x;
        mx = fmaxf(mx, x);
    }
    sred[tid] = mx;
    __syncthreads();
    for (int o = 256; o; o >>= 1) {
        if (tid < o) sred[tid] = fmaxf(sred[tid], sred[tid + o]);
        __syncthreads();
    }
    mx = sred[0];
    __syncthreads();

    float sm = 0.f;
    for (int n = tid; n < N_MEM; n += 512) sm += __expf(xbuf[n] - mx);
    sred[tid] = sm;
    __syncthreads();
    for (int o = 256; o; o >>= 1) {
        if (tid < o) sred[tid] += sred[tid + o];
        __syncthreads();
    }
    const float inv = 1.f / sred[0];
    __syncthreads();

    for (int n = tid; n < N_MEM; n += 512)
        w[n * B_KEYS + b] = __expf(xbuf[n] - mx) * inv;
}

// partial[s][b][d] = sum_{n in split s} w[n][b] * mem[n][d]
// grid: 98 d-blocks x ns splits. block 256 = 4 waves; wave bg owns b-group
// bg*8..bg*8+7; 64 lanes own one float4 d-column (coalesced 1KB/load).
// w staged in LDS in 125-n chunks (16 KB -> 8 blocks/CU, 32 waves/CU).
// Depth-2 prefetch on the mem stream.
__global__ __launch_bounds__(256) void k_read(const float* __restrict__ mem,
                                              const float* __restrict__ w,
                                              float* __restrict__ partial,
                                              int nPerS) {
    const int db   = blockIdx.x % 98;
    const int s    = blockIdx.x / 98;
    const int n0   = s * nPerS;
    const int bg   = threadIdx.x >> 6;          // 0..3, b0 = bg*8
    const int lane = threadIdx.x & 63;
    const int d4   = db * 64 + lane;            // float4 column, < 6272

    const float4* M4 = (const float4*)mem;
    const float4* W4 = (const float4*)w;
    __shared__ float4 wls4[125 * 8];            // 125 n x 32 b = 16 KB

    float acc[8][4];
#pragma unroll
    for (int i = 0; i < 8; ++i)
#pragma unroll
        for (int j = 0; j < 4; ++j) acc[i][j] = 0.f;

    for (int c0 = 0; c0 < nPerS; c0 += 125) {
        const int cn = min(125, nPerS - c0);
        __syncthreads();
        for (int i = threadIdx.x; i < cn * 8; i += 256)
            wls4[i] = W4[(n0 + c0) * 8 + i];
        __syncthreads();

        float4 mv[2];
        mv[0] = M4[(size_t)(n0 + c0) * D4 + d4];
        mv[1] = M4[(size_t)(n0 + c0 + 1) * D4 + d4];
        for (int nn = 0; nn < cn; ++nn) {
            const int cur = nn & 1;
            const float4 mc = mv[cur];
            if (nn + 2 < cn)                     // wave-uniform branch
                mv[cur] = M4[(size_t)(n0 + c0 + nn + 2) * D4 + d4];
            const float4 wa = wls4[nn * 8 + bg * 2];
            const float4 wb = wls4[nn * 8 + bg * 2 + 1];
            const float wv[8] = {wa.x, wa.y, wa.z, wa.w, wb.x, wb.y, wb.z, wb.w};
#pragma unroll
            for (int i = 0; i < 8; ++i) {
                acc[i][0] += wv[i] * mc.x;
                acc[i][1] += wv[i] * mc.y;
                acc[i][2] += wv[i] * mc.z;
                acc[i][3] += wv[i] * mc.w;
            }
        }
    }

    float4* P4 = (float4*)partial;
#pragma unroll
    for (int i = 0; i < 8; ++i)
        P4[(size_t)(s * B_KEYS + bg * 8 + i) * D4 + d4] =
            make_float4(acc[i][0], acc[i][1], acc[i][2], acc[i][3]);
}

__global__ __launch_bounds__(256) void k_finish(const float* __restrict__ partial,
                                                float* __restrict__ out, int ns) {
    const int i = blockIdx.x * 256 + threadIdx.x;   // float4 index, grid 784*256
    const float4* P4 = (const float4*)partial;
    float4 sum = P4[i];
    for (int s = 1; s < ns; ++s) {
        const float4 p = P4[(size_t)s * (B_KEYS * D4) + i];
        sum.x += p.x; sum.y += p.y; sum.z += p.z; sum.w += p.w;
    }
    ((float4*)out)[i] = sum;
}

extern "C" void kernel_launch(void* const* d_in, const int* in_sizes, int n_in,
                              void* d_out, int out_size, void* d_ws, size_t ws_size,
                              hipStream_t stream) {
    (void)in_sizes; (void)n_in; (void)out_size;
    const float* key = (const float*)d_in[0];
    const float* mem = (const float*)d_in[1];
    float* out = (float*)d_out;
    float* ws  = (float*)d_ws;

    short* keyb      = (short*)ws;      // 802816 shorts = 401408 floats
    float* dots_part = ws + 401408;     // 1024000 floats
    float* mn2_part  = ws + 1425408;    // 32000 floats
    float* w         = ws + 1457408;    // 64000 floats (16B aligned)
    float* part      = ws + 1521408;    // ns * 802816 floats (16B aligned)

    int ns = 8;   // n-splits for k_read (all candidates divide 2000)
    while (ns > 1 && (size_t)(1521408 + (size_t)ns * 802816) * 4 > ws_size) ns >>= 1;
    const int nPerS = N_MEM / ns;

    k_prep     <<<784, 256, 0, stream>>>(key, keyb);
    k_dots_mfma<<<125 * NSLICE, 64, 0, stream>>>(keyb, mem, dots_part, mn2_part);
    k_softmax  <<<B_KEYS, 512, 0, stream>>>(key, dots_part, mn2_part, w);
    k_read     <<<98 * ns, 256, 0, stream>>>(mem, w, part, nPerS);
    k_finish   <<<784, 256, 0, stream>>>(part, out, ns);
}

// Round 6
// 396.887 us; speedup vs baseline: 1.7511x; 1.7511x over previous
//
#include <hip/hip_runtime.h>
#include <math.h>

// Problem constants
#define D_ELEMS 25088   // C*H*W = 512*7*7
#define D4      6272    // D_ELEMS / 4
#define N_MEM   2000
#define B_KEYS  32
#define PI_2F   1.570795f   // 3.14159 / 2, matches reference
#define EPSF    1e-8f
#define NSLICE  16          // k-slices for k_dots_mfma (2000 waves = 2/SIMD)
#define KSLICE  1568        // 25088 / 16
#define KSTEPS  49          // KSLICE / 32

using short8 = __attribute__((ext_vector_type(8))) short;   // 8 bf16 A/B frag
using short4v = __attribute__((ext_vector_type(4))) short;
using f32x4  = __attribute__((ext_vector_type(4))) float;   // C/D frag

// ws layout (floats):
//   keyb (bf16 keys, as shorts)   : [0, 401408)
//   dots_part [16][2000][32]      : [401408, 1425408)
//   mn2_part  [16][2000]          : [1425408, 1457408)
//   dots      [2000][32]          : [1457408, 1521408)
//   mn2       [2000]              : [1521408, 1523408)
//   w         [2000][32]          : [1523456, 1587456)
//   partial [ns][32][25088]       : [1587456, +ns*802816)

__device__ inline short f2bf(float x) {   // fp32 -> bf16 RNE (inputs finite)
    union { float f; unsigned u; } v; v.f = x;
    unsigned r = v.u + 0x7fffu + ((v.u >> 16) & 1u);
    return (short)(r >> 16);
}

// Convert keys fp32 -> bf16 once. 802816 elems, 4 per thread.
__global__ __launch_bounds__(256) void k_prep(const float* __restrict__ key,
                                              short* __restrict__ keyb) {
    const int i = blockIdx.x * 256 + threadIdx.x;   // float4 index, grid 784*256
    const float4 f = ((const float4*)key)[i];
    short4v s; s[0] = f2bf(f.x); s[1] = f2bf(f.y); s[2] = f2bf(f.z); s[3] = f2bf(f.w);
    ((short4v*)keyb)[i] = s;
}

// dots_part[s][n][b] = sum_{k in slice s} key[b][k]*mem[n][k]  (bf16 MFMA)
// mn2_part[s][n]     = sum_{k in slice s} mem[n][k]^2          (fp32)
// grid: 125 n-tiles x 16 slices = 2000 blocks of 1 wave. Depth-1 prefetch
// with EXPLICIT named registers only (runtime-indexed local arrays demote
// to scratch -- the R4 regression).
__global__ __launch_bounds__(64) void k_dots_mfma(const short* __restrict__ keyb,
                                                  const float* __restrict__ mem,
                                                  float* __restrict__ dots_part,
                                                  float* __restrict__ mn2_part) {
    const int nt   = blockIdx.x / NSLICE;     // 0..124
    const int s    = blockIdx.x % NSLICE;     // 0..15
    const int n0   = nt * 16;
    const int lane = threadIdx.x;             // 0..63
    const int quad = lane >> 4;
    const int l16  = lane & 15;
    const int k0   = s * KSLICE + quad * 8;   // this lane's k base (floats)

    const short* a0p = keyb + (size_t)l16 * D_ELEMS + k0;          // keys 0..15
    const short* a1p = keyb + (size_t)(16 + l16) * D_ELEMS + k0;   // keys 16..31
    const float4* bp = (const float4*)(mem + (size_t)(n0 + l16) * D_ELEMS + k0);

    f32x4 acc0 = {0.f, 0.f, 0.f, 0.f};
    f32x4 acc1 = {0.f, 0.f, 0.f, 0.f};
    float msq = 0.f;

    // depth-1 prefetch: loads for step t+1 issue before the cvt+mfma of t
    short8 a0 = *(const short8*)a0p;
    short8 a1 = *(const short8*)a1p;
    float4 f0 = bp[0], f1 = bp[1];

    for (int t = 0; t < KSTEPS; ++t) {
        const short8 a0c = a0, a1c = a1;
        const float4 f0c = f0, f1c = f1;
        if (t + 1 < KSTEPS) {                 // wave-uniform branch
            a0 = *(const short8*)(a0p + (t + 1) * 32);
            a1 = *(const short8*)(a1p + (t + 1) * 32);
            f0 = bp[(t + 1) * 8];
            f1 = bp[(t + 1) * 8 + 1];
        }
        msq += f0c.x * f0c.x + f0c.y * f0c.y + f0c.z * f0c.z + f0c.w * f0c.w
             + f1c.x * f1c.x + f1c.y * f1c.y + f1c.z * f1c.z + f1c.w * f1c.w;
        short8 b;
        b[0] = f2bf(f0c.x); b[1] = f2bf(f0c.y); b[2] = f2bf(f0c.z); b[3] = f2bf(f0c.w);
        b[4] = f2bf(f1c.x); b[5] = f2bf(f1c.y); b[6] = f2bf(f1c.z); b[7] = f2bf(f1c.w);
        acc0 = __builtin_amdgcn_mfma_f32_16x16x32_bf16(a0c, b, acc0, 0, 0, 0);
        acc1 = __builtin_amdgcn_mfma_f32_16x16x32_bf16(a1c, b, acc1, 0, 0, 0);
    }

    // D[row=quad*4+r][col=l16]; row = key index (per m-half), col = n index
    float* dp = dots_part + (size_t)(s * N_MEM + n0 + l16) * B_KEYS;
#pragma unroll
    for (int r = 0; r < 4; ++r) {
        dp[quad * 4 + r]      = acc0[r];
        dp[16 + quad * 4 + r] = acc1[r];
    }

    // reduce msq across the 4 quads of each n-row (lanes l16, l16+16, ...)
    msq += __shfl_xor(msq, 16, 64);
    msq += __shfl_xor(msq, 32, 64);
    if (lane < 16) mn2_part[s * N_MEM + n0 + lane] = msq;
}

// Collapse the 16 slice partials: dots[n][b], mn2[n]. Coalesced. grid 250.
__global__ __launch_bounds__(256) void k_reduce(const float* __restrict__ dots_part,
                                                const float* __restrict__ mn2_part,
                                                float* __restrict__ dots,
                                                float* __restrict__ mn2) {
    const int gid = blockIdx.x * 256 + threadIdx.x;   // 0..63999
    float ds = 0.f;
#pragma unroll
    for (int s = 0; s < NSLICE; ++s) ds += dots_part[s * (N_MEM * B_KEYS) + gid];
    dots[gid] = ds;
    if (gid < N_MEM) {
        float ms = 0.f;
#pragma unroll
        for (int s = 0; s < NSLICE; ++s) ms += mn2_part[s * N_MEM + gid];
        mn2[gid] = ms;
    }
}

// per-b: k_norm (fp32 keys) -> cos -> tan -> softmax over n -> w.
__global__ __launch_bounds__(512) void k_softmax(const float* __restrict__ key,
                                                 const float* __restrict__ dots,
                                                 const float* __restrict__ mn2,
                                                 float* __restrict__ w) {
    const int b   = blockIdx.x;
    const int tid = threadIdx.x;
    __shared__ float sred[512];
    __shared__ float xbuf[N_MEM];

    const float4* K4 = (const float4*)(key + (size_t)b * D_ELEMS);
    float ks = 0.f;
    for (int i = tid; i < D4; i += 512) {
        float4 kf = K4[i];
        ks += kf.x * kf.x + kf.y * kf.y + kf.z * kf.z + kf.w * kf.w;
    }
    sred[tid] = ks;
    __syncthreads();
    for (int o = 256; o; o >>= 1) {
        if (tid < o) sred[tid] += sred[tid + o];
        __syncthreads();
    }
    const float knorm = fmaxf(sqrtf(sred[0]), EPSF);
    __syncthreads();

    float mx = -1e30f;
    for (int n = tid; n < N_MEM; n += 512) {
        float mn = fmaxf(sqrtf(mn2[n]), EPSF);
        float x  = __tanf((dots[n * B_KEYS + b] / (knorm * mn)) * PI_2F);
        xbuf[n] = x;
        mx = fmaxf(mx, x);
    }
    sred[tid] = mx;
    __syncthreads();
    for (int o = 256; o; o >>= 1) {
        if (tid < o) sred[tid] = fmaxf(sred[tid], sred[tid + o]);
        __syncthreads();
    }
    mx = sred[0];
    __syncthreads();

    float sm = 0.f;
    for (int n = tid; n < N_MEM; n += 512) sm += __expf(xbuf[n] - mx);
    sred[tid] = sm;
    __syncthreads();
    for (int o = 256; o; o >>= 1) {
        if (tid < o) sred[tid] += sred[tid + o];
        __syncthreads();
    }
    const float inv = 1.f / sred[0];
    __syncthreads();

    for (int n = tid; n < N_MEM; n += 512)
        w[n * B_KEYS + b] = __expf(xbuf[n] - mx) * inv;
}

// partial[s][b][d] = sum_{n in split s} w[n][b] * mem[n][d]
// grid: 98 d-blocks x ns splits. block 256 = 4 waves; wave bg owns b-group
// bg*8..bg*8+7; 64 lanes own one float4 d-column (coalesced 1KB/load).
// w staged in 250-n LDS tiles (32 KB). Depth-2 prefetch via manual 2x unroll
// with NAMED registers mv0/mv1 (no runtime-indexed arrays -> no scratch).
__global__ __launch_bounds__(256, 3) void k_read(const float* __restrict__ mem,
                                                 const float* __restrict__ w,
                                                 float* __restrict__ partial,
                                                 int nPerS) {
    const int db   = blockIdx.x % 98;
    const int s    = blockIdx.x / 98;
    const int n0   = s * nPerS;
    const int bg   = threadIdx.x >> 6;          // 0..3, b0 = bg*8
    const int lane = threadIdx.x & 63;
    const int d4   = db * 64 + lane;            // float4 column, < 6272

    const float4* M4 = (const float4*)mem;
    const float4* W4 = (const float4*)w;
    __shared__ float4 wls4[250 * 8];            // 250 n x 32 b = 32 KB

    float acc[8][4];
#pragma unroll
    for (int i = 0; i < 8; ++i)
#pragma unroll
        for (int j = 0; j < 4; ++j) acc[i][j] = 0.f;

    for (int c0 = 0; c0 < nPerS; c0 += 250) {   // cn == 250 always (nPerS % 250 == 0)
        const int cn = 250;
        __syncthreads();
        for (int i = threadIdx.x; i < cn * 8; i += 256)
            wls4[i] = W4[(n0 + c0) * 8 + i];
        __syncthreads();

        const float4* mp = M4 + (size_t)(n0 + c0) * D4 + d4;
        float4 mv0 = mp[0];
        float4 mv1 = mp[(size_t)D4];
        for (int nn = 0; nn < cn; nn += 2) {
            // --- sub-iter 0 ---
            const float4 mc0 = mv0;
            const int i2 = (nn + 2 < cn) ? nn + 2 : cn - 2;
            mv0 = mp[(size_t)i2 * D4];
            {
                const float4 wa = wls4[nn * 8 + bg * 2];
                const float4 wb = wls4[nn * 8 + bg * 2 + 1];
                const float wv[8] = {wa.x, wa.y, wa.z, wa.w, wb.x, wb.y, wb.z, wb.w};
#pragma unroll
                for (int i = 0; i < 8; ++i) {
                    acc[i][0] += wv[i] * mc0.x;
                    acc[i][1] += wv[i] * mc0.y;
                    acc[i][2] += wv[i] * mc0.z;
                    acc[i][3] += wv[i] * mc0.w;
                }
            }
            // --- sub-iter 1 ---
            const float4 mc1 = mv1;
            const int i3 = (nn + 3 < cn) ? nn + 3 : cn - 1;
            mv1 = mp[(size_t)i3 * D4];
            {
                const float4 wa = wls4[(nn + 1) * 8 + bg * 2];
                const float4 wb = wls4[(nn + 1) * 8 + bg * 2 + 1];
                const float wv[8] = {wa.x, wa.y, wa.z, wa.w, wb.x, wb.y, wb.z, wb.w};
#pragma unroll
                for (int i = 0; i < 8; ++i) {
                    acc[i][0] += wv[i] * mc1.x;
                    acc[i][1] += wv[i] * mc1.y;
                    acc[i][2] += wv[i] * mc1.z;
                    acc[i][3] += wv[i] * mc1.w;
                }
            }
        }
    }

    float4* P4 = (float4*)partial;
#pragma unroll
    for (int i = 0; i < 8; ++i)
        P4[(size_t)(s * B_KEYS + bg * 8 + i) * D4 + d4] =
            make_float4(acc[i][0], acc[i][1], acc[i][2], acc[i][3]);
}

__global__ __launch_bounds__(256) void k_finish(const float* __restrict__ partial,
                                                float* __restrict__ out, int ns) {
    const int i = blockIdx.x * 256 + threadIdx.x;   // float4 index, grid 784*256
    const float4* P4 = (const float4*)partial;
    float4 sum = P4[i];
    for (int s = 1; s < ns; ++s) {
        const float4 p = P4[(size_t)s * (B_KEYS * D4) + i];
        sum.x += p.x; sum.y += p.y; sum.z += p.z; sum.w += p.w;
    }
    ((float4*)out)[i] = sum;
}

extern "C" void kernel_launch(void* const* d_in, const int* in_sizes, int n_in,
                              void* d_out, int out_size, void* d_ws, size_t ws_size,
                              hipStream_t stream) {
    (void)in_sizes; (void)n_in; (void)out_size;
    const float* key = (const float*)d_in[0];
    const float* mem = (const float*)d_in[1];
    float* out = (float*)d_out;
    float* ws  = (float*)d_ws;

    short* keyb      = (short*)ws;      // 802816 shorts = 401408 floats
    float* dots_part = ws + 401408;     // 1024000 floats
    float* mn2_part  = ws + 1425408;    // 32000 floats
    float* dots      = ws + 1457408;    // 64000 floats
    float* mn2       = ws + 1521408;    // 2000 floats
    float* w         = ws + 1523456;    // 64000 floats (16B aligned)
    float* part      = ws + 1587456;    // ns * 802816 floats (16B aligned)

    int ns = 8;   // n-splits for k_read (candidates divide 2000, mult of 250)
    while (ns > 1 && (size_t)(1587456 + (size_t)ns * 802816) * 4 > ws_size) ns >>= 1;
    const int nPerS = N_MEM / ns;

    k_prep     <<<784, 256, 0, stream>>>(key, keyb);
    k_dots_mfma<<<125 * NSLICE, 64, 0, stream>>>(keyb, mem, dots_part, mn2_part);
    k_reduce   <<<250, 256, 0, stream>>>(dots_part, mn2_part, dots, mn2);
    k_softmax  <<<B_KEYS, 512, 0, stream>>>(key, dots, mn2, w);
    k_read     <<<98 * ns, 256, 0, stream>>>(mem, w, part, nPerS);
    k_finish   <<<784, 256, 0, stream>>>(part, out, ns);
}